// Round 1
// baseline (808.362 us; speedup 1.0000x reference)
//
#include <hip/hip_runtime.h>

typedef unsigned int u32;
typedef unsigned short u16;
typedef float f32x4 __attribute__((ext_vector_type(4)));
typedef __bf16 bf16x8 __attribute__((ext_vector_type(8)));

#define N_IMG 32
#define C_IN 128
#define HW_DIM 112
#define C_OUT 256
#define PADD 114
#define PIX_PER_IMG (HW_DIM * HW_DIM)          // 12544
#define NPIX (N_IMG * PIX_PER_IMG)             // 401408
#define KTOT 1152                              // 9 * 128
#define IBUF_BYTES ((size_t)N_IMG * PADD * PADD * C_IN * 2)  // 106,463,232

// round-to-nearest-even fp32 -> bf16
__device__ __forceinline__ u16 f2bf(float f) {
  u32 u = __builtin_bit_cast(u32, f);
  u32 r = u + 0x7fffu + ((u >> 16) & 1u);
  return (u16)(r >> 16);
}

__device__ __forceinline__ void async16(const void* g, void* l) {
  __builtin_amdgcn_global_load_lds(
      (const __attribute__((address_space(1))) u32*)g,
      (__attribute__((address_space(3))) u32*)l, 16, 0, 0);
}

// ---- pre-pass 1: zero the 1-px halo of the padded NHWC bf16 buffer (3.7 MB, not 106 MB memset)
__global__ __launch_bounds__(256) void zero_border(u16* __restrict__ buf) {
  int g = blockIdx.x * 256 + threadIdx.x;      // 32 * 452 * 128 = 1,851,392 = 7232 * 256
  int n = g / (452 * 128);
  int r = g % (452 * 128);
  int pix = r >> 7;
  int ci = r & 127;
  int h, w;
  if (pix < 114)      { h = 0;         w = pix; }
  else if (pix < 228) { h = 113;       w = pix - 114; }
  else if (pix < 340) { h = pix - 227; w = 0; }
  else                { h = pix - 339; w = 113; }
  buf[((size_t)(n * PADD + h) * PADD + w) * C_IN + ci] = 0;
}

// ---- pre-pass 2: NCHW fp32 -> padded NHWC bf16 via LDS transpose (64 px x 128 ci per block)
__global__ __launch_bounds__(256) void convert_input(const float* __restrict__ in,
                                                     u16* __restrict__ buf) {
  __shared__ u32 lds[64 * 65];                 // [pixel][65 dw] (+1 dw pad: 2-way banks both phases)
  int tid = threadIdx.x;
  int b = blockIdx.x;                          // 32 * 196 = 6272
  int n = b / 196;
  int hwb = (b % 196) * 64;
  int lw = tid & 63;
  int wv = tid >> 6;
  const float* src = in + (size_t)n * C_IN * PIX_PER_IMG + hwb + lw;
#pragma unroll
  for (int cb = 0; cb < 4; ++cb)
#pragma unroll
    for (int j = 0; j < 4; ++j) {
      int c = cb * 16 + wv * 4 + j;            // ci pair (2c, 2c+1)
      float f0 = src[(size_t)(2 * c) * PIX_PER_IMG];
      float f1 = src[(size_t)(2 * c + 1) * PIX_PER_IMG];
      lds[lw * 65 + c] = (u32)f2bf(f0) | ((u32)f2bf(f1) << 16);
    }
  __syncthreads();
#pragma unroll
  for (int k = 0; k < 4; ++k) {
    int g = k * 256 + tid;                     // 1024 chunks of 16 B
    int row = g >> 4, ch = g & 15;
    u32 d0 = lds[row * 65 + ch * 4 + 0];
    u32 d1 = lds[row * 65 + ch * 4 + 1];
    u32 d2 = lds[row * 65 + ch * 4 + 2];
    u32 d3 = lds[row * 65 + ch * 4 + 3];
    int hw = hwb + row;
    int h = hw / HW_DIM, w = hw % HW_DIM;
    u32* dst = (u32*)(buf + ((size_t)(n * PADD + h + 1) * PADD + (w + 1)) * C_IN) + ch * 4;
    uint4 v; v.x = d0; v.y = d1; v.z = d2; v.w = d3;
    *(uint4*)dst = v;
  }
}

// ---- pre-pass 3: OIHW fp32 -> [co][kh][kw][ci] bf16 (K-order matches A staging)
__global__ __launch_bounds__(256) void convert_weight(const float* __restrict__ w,
                                                      u16* __restrict__ wt) {
  int g = blockIdx.x * 256 + threadIdx.x;      // 294912 = 1152 * 256
  int co = g / KTOT;
  int r = g % KTOT;
  int f = r >> 7;                              // kh*3+kw
  int ci = r & 127;
  wt[g] = f2bf(w[(size_t)(co * C_IN + ci) * 9 + f]);
}

// ---- main: implicit-GEMM conv, 128(co) x 128(pix) tile, BK=64, mfma 16x16x32 bf16
__global__ __launch_bounds__(256) void conv_mfma(const u16* __restrict__ ibuf,
                                                 const u16* __restrict__ wbuf,
                                                 const float* __restrict__ bias,
                                                 float* __restrict__ out) {
  __shared__ __attribute__((aligned(16))) char smem[16384 * 2 + 1024];
  char* ldsA = smem;                           // weights tile: 128 co x 64 k bf16
  char* ldsB = smem + 16384;                   // pixel tile:  128 px x 64 k bf16
  float* ldsBias = (float*)(smem + 32768);

  int tid = threadIdx.x;
  int lane = tid & 63;
  int wv = tid >> 6;
  // T1: XCD-aware bijective swizzle. grid = 6272 = 8 * 784; hardware round-robins
  // blockIdx.x % 8 across XCDs, so each XCD gets a CONTIGUOUS 784-block work chunk:
  // co-pair blocks (work 2k, 2k+1) and pixel-adjacent tiles share one XCD's L2.
  int bi0 = blockIdx.x;
  int bi = (bi0 & 7) * 784 + (bi0 >> 3);       // 3136 pix-tiles * 2 co-tiles = 6272
  int co_tile = bi & 1;
  int pix_tile = bi >> 1;
  int pb = pix_tile * 128;
  int co_base = co_tile * 128;

  ldsBias[tid] = bias[tid];                    // 256 threads == 256 co

  // staging address precompute: 4 rounds x 16 B per thread per tile; XOR chunk swizzle
  const char* gA[4];
  const char* gB[4];
#pragma unroll
  for (int j = 0; j < 4; ++j) {
    int r = j * 32 + (tid >> 3);               // row 0..127
    int cg = (tid & 7) ^ (r & 7);              // global chunk for this lane's LDS slot
    gA[j] = (const char*)wbuf + (size_t)(co_base + r) * (KTOT * 2) + cg * 16;
    int pid = pb + r;                          // 12544 = 98*128 -> tile never crosses images
    int n = pid / PIX_PER_IMG;
    int hw = pid % PIX_PER_IMG;
    int h = hw / HW_DIM, w = hw % HW_DIM;
    gB[j] = (const char*)ibuf + ((size_t)(n * PADD + h) * PADD + w) * (C_IN * 2) + cg * 16;
  }

  f32x4 acc[4][4] = {};
  int wm = wv & 1;                             // co half
  int wn = wv >> 1;                            // pixel half
  int q = lane >> 4;
  int lr = lane & 15;

  for (int s = 0; s < 18; ++s) {               // K = 18 * 64, each stage = one filter tap half
    __syncthreads();
    int offA = s * 128;                        // bytes into [co][1152] row
    int f = s >> 1;
    int kh = (f * 11) >> 5;                    // f/3 for f<9
    int kw = f - kh * 3;
    int offB = (kh * PADD + kw) * (C_IN * 2) + (s & 1) * 128;
#pragma unroll
    for (int j = 0; j < 4; ++j) {
      async16(gA[j] + offA, ldsA + (j * 256 + wv * 64) * 16);
      async16(gB[j] + offB, ldsB + (j * 256 + wv * 64) * 16);
    }
    __syncthreads();
#pragma unroll
    for (int kb = 0; kb < 2; ++kb) {
      bf16x8 af[4], bf[4];
#pragma unroll
      for (int mt = 0; mt < 4; ++mt) {
        int row = wm * 64 + mt * 16 + lr;
        int ch = (kb * 4 + q) ^ (row & 7);
        af[mt] = *(const bf16x8*)(ldsA + row * 128 + ch * 16);
      }
#pragma unroll
      for (int nt = 0; nt < 4; ++nt) {
        int row = wn * 64 + nt * 16 + lr;
        int ch = (kb * 4 + q) ^ (row & 7);
        bf[nt] = *(const bf16x8*)(ldsB + row * 128 + ch * 16);
      }
#pragma unroll
      for (int mt = 0; mt < 4; ++mt)
#pragma unroll
        for (int nt = 0; nt < 4; ++nt)
          acc[mt][nt] = __builtin_amdgcn_mfma_f32_16x16x32_bf16(af[mt], bf[nt], acc[mt][nt], 0, 0, 0);
    }
  }

  // epilogue: D[m=co][n=pix], lane holds rows q*4+r, col lr; 16-lane-contiguous stores
  int n_img = pb / PIX_PER_IMG;                // block-uniform
  int hw_base = pb % PIX_PER_IMG;
  float* outp = out + (size_t)n_img * C_OUT * PIX_PER_IMG + hw_base;
#pragma unroll
  for (int mt = 0; mt < 4; ++mt) {
    int co0 = co_base + wm * 64 + mt * 16 + q * 4;
    float4 bv = *(const float4*)&ldsBias[co0];
    const float* bvp = (const float*)&bv;
#pragma unroll
    for (int nt = 0; nt < 4; ++nt) {
      int pix = wn * 64 + nt * 16 + lr;
#pragma unroll
      for (int r = 0; r < 4; ++r)
        outp[(size_t)(co0 + r) * PIX_PER_IMG + pix] = acc[mt][nt][r] + bvp[r];
    }
  }
}

extern "C" void kernel_launch(void* const* d_in, const int* in_sizes, int n_in,
                              void* d_out, int out_size, void* d_ws, size_t ws_size,
                              hipStream_t stream) {
  (void)in_sizes; (void)n_in; (void)out_size; (void)ws_size;
  const float* img = (const float*)d_in[0];
  const float* wgt = (const float*)d_in[1];
  const float* bias = (const float*)d_in[2];
  float* out = (float*)d_out;
  u16* ibuf = (u16*)d_ws;                                   // 106.5 MB padded NHWC bf16
  u16* wbuf = (u16*)((char*)d_ws + IBUF_BYTES);             // 0.59 MB bf16 weights

  zero_border<<<7232, 256, 0, stream>>>(ibuf);
  convert_input<<<6272, 256, 0, stream>>>(img, ibuf);
  convert_weight<<<1152, 256, 0, stream>>>(wgt, wbuf);
  conv_mfma<<<6272, 256, 0, stream>>>(ibuf, wbuf, bias, out);
}

// Round 2
// 753.452 us; speedup vs baseline: 1.0729x; 1.0729x over previous
//
#include <hip/hip_runtime.h>

typedef unsigned int u32;
typedef unsigned short u16;
typedef float f32x4 __attribute__((ext_vector_type(4)));
typedef __bf16 bf16x8 __attribute__((ext_vector_type(8)));

#define N_IMG 32
#define C_IN 128
#define HW_DIM 112
#define C_OUT 256
#define PADD 114
#define PIX_PER_IMG (HW_DIM * HW_DIM)          // 12544
#define NPIX (N_IMG * PIX_PER_IMG)             // 401408
#define KTOT 1152                              // 9 * 128
#define IBUF_BYTES ((size_t)N_IMG * PADD * PADD * C_IN * 2)  // 106,463,232

// round-to-nearest-even fp32 -> bf16
__device__ __forceinline__ u16 f2bf(float f) {
  u32 u = __builtin_bit_cast(u32, f);
  u32 r = u + 0x7fffu + ((u >> 16) & 1u);
  return (u16)(r >> 16);
}

__device__ __forceinline__ void async16(const void* g, void* l) {
  __builtin_amdgcn_global_load_lds(
      (const __attribute__((address_space(1))) u32*)g,
      (__attribute__((address_space(3))) u32*)l, 16, 0, 0);
}

// ---- pre-pass 1: zero the 1-px halo of the padded NHWC bf16 buffer (3.7 MB, not 106 MB memset)
__global__ __launch_bounds__(256) void zero_border(u16* __restrict__ buf) {
  int g = blockIdx.x * 256 + threadIdx.x;      // 32 * 452 * 128 = 1,851,392 = 7232 * 256
  int n = g / (452 * 128);
  int r = g % (452 * 128);
  int pix = r >> 7;
  int ci = r & 127;
  int h, w;
  if (pix < 114)      { h = 0;         w = pix; }
  else if (pix < 228) { h = 113;       w = pix - 114; }
  else if (pix < 340) { h = pix - 227; w = 0; }
  else                { h = pix - 339; w = 113; }
  buf[((size_t)(n * PADD + h) * PADD + w) * C_IN + ci] = 0;
}

// ---- pre-pass 2: NCHW fp32 -> padded NHWC bf16 via LDS transpose (64 px x 128 ci per block)
__global__ __launch_bounds__(256) void convert_input(const float* __restrict__ in,
                                                     u16* __restrict__ buf) {
  __shared__ u32 lds[64 * 65];                 // [pixel][65 dw] (+1 dw pad: 2-way banks both phases)
  int tid = threadIdx.x;
  int b = blockIdx.x;                          // 32 * 196 = 6272
  int n = b / 196;
  int hwb = (b % 196) * 64;
  int lw = tid & 63;
  int wv = tid >> 6;
  const float* src = in + (size_t)n * C_IN * PIX_PER_IMG + hwb + lw;
#pragma unroll
  for (int cb = 0; cb < 4; ++cb)
#pragma unroll
    for (int j = 0; j < 4; ++j) {
      int c = cb * 16 + wv * 4 + j;            // ci pair (2c, 2c+1)
      float f0 = src[(size_t)(2 * c) * PIX_PER_IMG];
      float f1 = src[(size_t)(2 * c + 1) * PIX_PER_IMG];
      lds[lw * 65 + c] = (u32)f2bf(f0) | ((u32)f2bf(f1) << 16);
    }
  __syncthreads();
#pragma unroll
  for (int k = 0; k < 4; ++k) {
    int g = k * 256 + tid;                     // 1024 chunks of 16 B
    int row = g >> 4, ch = g & 15;
    u32 d0 = lds[row * 65 + ch * 4 + 0];
    u32 d1 = lds[row * 65 + ch * 4 + 1];
    u32 d2 = lds[row * 65 + ch * 4 + 2];
    u32 d3 = lds[row * 65 + ch * 4 + 3];
    int hw = hwb + row;
    int h = hw / HW_DIM, w = hw % HW_DIM;
    u32* dst = (u32*)(buf + ((size_t)(n * PADD + h + 1) * PADD + (w + 1)) * C_IN) + ch * 4;
    uint4 v; v.x = d0; v.y = d1; v.z = d2; v.w = d3;
    *(uint4*)dst = v;
  }
}

// ---- pre-pass 3: OIHW fp32 -> [co][kh][kw][ci] bf16 (K-order matches A staging)
__global__ __launch_bounds__(256) void convert_weight(const float* __restrict__ w,
                                                      u16* __restrict__ wt) {
  int g = blockIdx.x * 256 + threadIdx.x;      // 294912 = 1152 * 256
  int co = g / KTOT;
  int r = g % KTOT;
  int f = r >> 7;                              // kh*3+kw
  int ci = r & 127;
  wt[g] = f2bf(w[(size_t)(co * C_IN + ci) * 9 + f]);
}

// ---- main: implicit-GEMM conv, 128(co) x 128(pix) tile, BK=64, mfma 16x16x32 bf16
// T3+T4 schedule: double-buffered LDS, counted vmcnt(8) (never drain to 0 mid-loop),
// raw s_barrier (no compiler-inserted vmcnt(0) drain), T5 setprio around compute.
__global__ __launch_bounds__(256) void conv_mfma(const u16* __restrict__ ibuf,
                                                 const u16* __restrict__ wbuf,
                                                 const float* __restrict__ bias,
                                                 float* __restrict__ out) {
  // buf b: A tile at b*32768, B tile at b*32768+16384 (each 128 rows x 64 k bf16 = 16 KB)
  __shared__ __attribute__((aligned(16))) char smem[65536];

  int tid = threadIdx.x;
  int lane = tid & 63;
  int wv = tid >> 6;
  // T1: XCD-aware bijective swizzle. grid = 6272 = 8 * 784; hardware round-robins
  // blockIdx.x % 8 across XCDs, so each XCD gets a CONTIGUOUS 784-block work chunk.
  int bi0 = blockIdx.x;
  int bi = (bi0 & 7) * 784 + (bi0 >> 3);       // 3136 pix-tiles * 2 co-tiles = 6272
  int co_tile = bi & 1;
  int pix_tile = bi >> 1;
  int pb = pix_tile * 128;
  int co_base = co_tile * 128;

  // staging address precompute: 4 rounds x 16 B per thread per operand; XOR chunk swizzle
  // (LDS dest stays linear for global_load_lds; source address carries the swizzle)
  const char* gA[4];
  const char* gB[4];
#pragma unroll
  for (int j = 0; j < 4; ++j) {
    int r = j * 32 + (tid >> 3);               // row 0..127
    int cg = (tid & 7) ^ (r & 7);              // global chunk for this lane's LDS slot
    gA[j] = (const char*)wbuf + (size_t)(co_base + r) * (KTOT * 2) + cg * 16;
    int pid = pb + r;                          // 12544 = 98*128 -> tile never crosses images
    int n = pid / PIX_PER_IMG;
    int hw = pid % PIX_PER_IMG;
    int h = hw / HW_DIM, w = hw % HW_DIM;
    gB[j] = (const char*)ibuf + ((size_t)(n * PADD + h) * PADD + w) * (C_IN * 2) + cg * 16;
  }

  // stage K-tile t (t in 0..17) into buffer buf: 8 global_load_lds per thread
#define STAGE(t, buf)                                                          \
  do {                                                                         \
    int offA_ = (t) * 128;                                                     \
    int f_ = (t) >> 1;                                                         \
    int kh_ = (f_ * 11) >> 5;                                                  \
    int kw_ = f_ - kh_ * 3;                                                    \
    int offB_ = (kh_ * PADD + kw_) * (C_IN * 2) + ((t) & 1) * 128;             \
    char* dA_ = smem + (buf) * 32768;                                          \
    char* dB_ = dA_ + 16384;                                                   \
    _Pragma("unroll")                                                          \
    for (int j_ = 0; j_ < 4; ++j_) {                                           \
      async16(gA[j_] + offA_, dA_ + (j_ * 256 + wv * 64) * 16);                \
      async16(gB[j_] + offB_, dB_ + (j_ * 256 + wv * 64) * 16);                \
    }                                                                          \
  } while (0)

  f32x4 acc[4][4] = {};
  int wm = wv & 1;                             // co half
  int wn = wv >> 1;                            // pixel half
  int q = lane >> 4;
  int lr = lane & 15;

  // prologue: 2 K-tiles in flight (16 loads/thread outstanding)
  STAGE(0, 0);
  STAGE(1, 1);

  for (int t = 0; t < 18; ++t) {
    int cur = t & 1;
    // wait for K-tile t's 8 loads (oldest); K-tile t+1's 8 stay in flight across the barrier
    if (t == 17) { asm volatile("s_waitcnt vmcnt(0)" ::: "memory"); }
    else         { asm volatile("s_waitcnt vmcnt(8)" ::: "memory"); }
    __builtin_amdgcn_sched_barrier(0);
    __builtin_amdgcn_s_barrier();              // raw: no compiler vmcnt(0) drain
    __builtin_amdgcn_sched_barrier(0);

    const char* lA = smem + cur * 32768;
    const char* lB = lA + 16384;
    __builtin_amdgcn_s_setprio(1);
#pragma unroll
    for (int kb = 0; kb < 2; ++kb) {
      bf16x8 af[4], bf[4];
#pragma unroll
      for (int mt = 0; mt < 4; ++mt) {
        int row = wm * 64 + mt * 16 + lr;
        int ch = (kb * 4 + q) ^ (row & 7);
        af[mt] = *(const bf16x8*)(lA + row * 128 + ch * 16);
      }
#pragma unroll
      for (int nt = 0; nt < 4; ++nt) {
        int row = wn * 64 + nt * 16 + lr;
        int ch = (kb * 4 + q) ^ (row & 7);
        bf[nt] = *(const bf16x8*)(lB + row * 128 + ch * 16);
      }
#pragma unroll
      for (int mt = 0; mt < 4; ++mt)
#pragma unroll
        for (int nt = 0; nt < 4; ++nt)
          acc[mt][nt] = __builtin_amdgcn_mfma_f32_16x16x32_bf16(af[mt], bf[nt], acc[mt][nt], 0, 0, 0);
    }
    __builtin_amdgcn_s_setprio(0);
    __builtin_amdgcn_sched_barrier(0);
    __builtin_amdgcn_s_barrier();              // all waves done reading buf cur
    __builtin_amdgcn_sched_barrier(0);
    if (t + 2 < 18) STAGE(t + 2, cur);         // refill freed buffer; lands by iter t+2's vmcnt(8)
    __builtin_amdgcn_sched_barrier(0);
  }
#undef STAGE

  // epilogue: D[m=co][n=pix], lane holds rows q*4+r, col lr; 16-lane-contiguous stores
  int n_img = pb / PIX_PER_IMG;                // block-uniform
  int hw_base = pb % PIX_PER_IMG;
  float* outp = out + (size_t)n_img * C_OUT * PIX_PER_IMG + hw_base;
#pragma unroll
  for (int mt = 0; mt < 4; ++mt) {
    int co0 = co_base + wm * 64 + mt * 16 + q * 4;
    float4 bv = *(const float4*)&bias[co0];    // L2-hot, 16B-aligned (co0 % 4 == 0)
    const float* bvp = (const float*)&bv;
#pragma unroll
    for (int nt = 0; nt < 4; ++nt) {
      int pix = wn * 64 + nt * 16 + lr;
#pragma unroll
      for (int r = 0; r < 4; ++r)
        outp[(size_t)(co0 + r) * PIX_PER_IMG + pix] = acc[mt][nt][r] + bvp[r];
    }
  }
}

extern "C" void kernel_launch(void* const* d_in, const int* in_sizes, int n_in,
                              void* d_out, int out_size, void* d_ws, size_t ws_size,
                              hipStream_t stream) {
  (void)in_sizes; (void)n_in; (void)out_size; (void)ws_size;
  const float* img = (const float*)d_in[0];
  const float* wgt = (const float*)d_in[1];
  const float* bias = (const float*)d_in[2];
  float* out = (float*)d_out;
  u16* ibuf = (u16*)d_ws;                                   // 106.5 MB padded NHWC bf16
  u16* wbuf = (u16*)((char*)d_ws + IBUF_BYTES);             // 0.59 MB bf16 weights

  zero_border<<<7232, 256, 0, stream>>>(ibuf);
  convert_input<<<6272, 256, 0, stream>>>(img, ibuf);
  convert_weight<<<1152, 256, 0, stream>>>(wgt, wbuf);
  conv_mfma<<<6272, 256, 0, stream>>>(ibuf, wbuf, bias, out);
}